// Round 19
// baseline (169.248 us; speedup 1.0000x reference)
//
#include <hip/hip_runtime.h>
#include <math.h>

#define NTOK 16384
#define DIM  4096
#define NE   64
#define TOPK 8
#define WFL   128               // floats per row per window (512B)
#define NWIN  (DIM / WFL)       // 32 windows, 4 k32-slices each
#define SLOTF (64 * WFL)        // floats per ring slot (64 rows)
#define ROUTE_SCALE 2.5f

typedef __attribute__((ext_vector_type(8))) short short8v;
typedef __attribute__((ext_vector_type(4))) float f32x4;

// exact 3-term bf16 truncation split of 8 f32, packed as 3x short8 (bf16) frags
__device__ __forceinline__ void split3_pack(const float* v, uint4& b0, uint4& b1, uint4& b2)
{
    uint p0[8], p1[8], p2[8];
#pragma unroll
    for (int j = 0; j < 8; ++j) {
        const float xv = v[j];
        const uint  u0 = __float_as_uint(xv) & 0xffff0000u;
        const float f0 = __uint_as_float(u0);
        const float r  = xv - f0;                       // exact
        const uint  u1 = __float_as_uint(r) & 0xffff0000u;
        const float f1 = __uint_as_float(u1);
        const float r2 = r - f1;                        // exact, fits bf16
        const uint  u2 = __float_as_uint(r2) & 0xffff0000u;
        p0[j] = u0; p1[j] = u1; p2[j] = u2;
    }
    b0 = make_uint4(p0[1] | (p0[0] >> 16), p0[3] | (p0[2] >> 16),
                    p0[5] | (p0[4] >> 16), p0[7] | (p0[6] >> 16));
    b1 = make_uint4(p1[1] | (p1[0] >> 16), p1[3] | (p1[2] >> 16),
                    p1[5] | (p1[4] >> 16), p1[7] | (p1[6] >> 16));
    b2 = make_uint4(p2[1] | (p2[0] >> 16), p2[3] | (p2[2] >> 16),
                    p2[5] | (p2[4] >> 16), p2[7] | (p2[6] >> 16));
}

// ---- prep: w -> frag-ready bf16 splits (UNCHANGED, proven r4-r18) ----
__global__ __launch_bounds__(256)
void prep_w(const float* __restrict__ gw, uint4* __restrict__ wS)
{
    const int tid  = blockIdx.x * 256 + threadIdx.x;   // 32768 total
    const int lane = tid & 63;
    const int nt   = (tid >> 6) & 3;
    const int ks   = tid >> 8;                         // 0..127
    const int e    = nt * 16 + (lane & 15);
    const int kb   = ks * 32 + (lane >> 4) * 8;
    float v[8];
    *(float4*)&v[0] = *(const float4*)&gw[(size_t)e * DIM + kb];
    *(float4*)&v[4] = *(const float4*)&gw[(size_t)e * DIM + kb + 4];
    uint4 b0, b1, b2;
    split3_pack(v, b0, b1, b2);
    const size_t base = (size_t)(ks * 4 + nt) * 3 * 64 + lane;
    wS[base] = b0; wS[base + 64] = b1; wS[base + 128] = b2;
}

__device__ __forceinline__ void gld_lds16(const float* g, float* l)
{
    __builtin_amdgcn_global_load_lds(
        (const __attribute__((address_space(1))) unsigned int*)g,
        (__attribute__((address_space(3))) unsigned int*)l,
        16, 0, 0);
}

#define MFMA6(A0, A1, A2, B0, B1, B2, ACC) do {                              \
    ACC = __builtin_amdgcn_mfma_f32_16x16x32_bf16(A2, B0, ACC, 0, 0, 0);     \
    ACC = __builtin_amdgcn_mfma_f32_16x16x32_bf16(A1, B1, ACC, 0, 0, 0);     \
    ACC = __builtin_amdgcn_mfma_f32_16x16x32_bf16(A0, B2, ACC, 0, 0, 0);     \
    ACC = __builtin_amdgcn_mfma_f32_16x16x32_bf16(A1, B0, ACC, 0, 0, 0);     \
    ACC = __builtin_amdgcn_mfma_f32_16x16x32_bf16(A0, B1, ACC, 0, 0, 0);     \
    ACC = __builtin_amdgcn_mfma_f32_16x16x32_bf16(A0, B0, ACC, 0, 0, 0);     \
} while (0)

#define SB __builtin_amdgcn_sched_barrier(0)
#define WAIT1 do { SB; asm volatile("s_waitcnt vmcnt(1)" ::: "memory"); SB; } while (0)
#define WAIT0 do { SB; asm volatile("s_waitcnt vmcnt(0)" ::: "memory"); SB; } while (0)

// ---- fused: 64 tok x 64 exp x full-K per block; 8 waves (2M x 4N);
// 512B/row contiguous DMA, 3-slot ring, uniform vmcnt(1), 1 barrier/superturn ----
__global__ __launch_bounds__(512)
void router_fused(const float* __restrict__ x, const uint4* __restrict__ wS,
                  const float* __restrict__ bias, float* __restrict__ out)
{
    __shared__ float pool[3 * SLOTF];      // 96 KB ring (DMA dest, linear)
    __shared__ float sc[64][NE + 1];       // 16.6 KB
    __shared__ int   hist[NE];

    const int t    = threadIdx.x;
    const int lane = t & 63;
    const int wv   = __builtin_amdgcn_readfirstlane(t >> 6);   // 0..7
    const int wr   = wv >> 2;              // token half (0..1)
    const int wc   = wv & 3;               // expert quarter (nt)
    const int r15  = lane & 15;
    const int g    = lane >> 4;
    const int tok0 = blockIdx.x * 64;

    if (t < NE) hist[t] = 0;

    // DMA piece j (0..3): rows wv*8+2j (+ lane>>5); pre-swizzled source granule
    // (m173): within the 512B window lane l reads granule (l&31) ^ (row&7).
    const int prow = lane >> 5;                       // 0..1 within piece
#define GSRC(j) (x + (size_t)(tok0 + wv * 8 + 2 * (j) + prow) * DIM \
                   + (size_t)((lane & 31) ^ ((2 * (j) + prow) & 7)) * 4)
    const float* gsrc0 = GSRC(0);
    const float* gsrc1 = GSRC(1);
    const float* gsrc2 = GSRC(2);
    const float* gsrc3 = GSRC(3);
#undef GSRC

    const uint4* wq = wS + lane;

    f32x4 acc0 = {0.f, 0.f, 0.f, 0.f};
    f32x4 acc1 = {0.f, 0.f, 0.f, 0.f};
    uint4 B0v, B1v, B2v;

#define DP(j, q, wdw) do {                                                   \
        float* d = &pool[(q) * SLOTF + (wv * 8 + 2 * (j)) * WFL];            \
        gld_lds16(gsrc##j + (size_t)(wdw) * WFL, d);                         \
    } while (0)
#define LOADB(sg) do {                                                       \
        const size_t bb = (size_t)(sg) * 768 + (size_t)wc * 192;             \
        B0v = wq[bb]; B1v = wq[bb + 64]; B2v = wq[bb + 128];                 \
    } while (0)
// A granule (16B idx 0..31) for slice-in-window ws, part b: swizzled by row&7(=r15&7)
#define QA(ws, b) ((((ws) * 8 + 2 * g + (b)) ^ (r15 & 7)) * 4)
#define SLICEBODY(s_, p_) do {                                               \
        const float* sbp = &pool[(p_) * SLOTF];                              \
        const int ws = (s_) & 3;                                             \
        float a8[8]; uint4 u0, u1, u2;                                       \
        { const int rb = (wr * 32 + r15) * WFL;                              \
          *(float4*)&a8[0] = *(const float4*)&sbp[rb + QA(ws, 0)];           \
          *(float4*)&a8[4] = *(const float4*)&sbp[rb + QA(ws, 1)]; }         \
        split3_pack(a8, u0, u1, u2);                                         \
        const short8v A00 = *(short8v*)&u0, A10 = *(short8v*)&u1, A20 = *(short8v*)&u2; \
        { const int rb = (wr * 32 + 16 + r15) * WFL;                         \
          *(float4*)&a8[0] = *(const float4*)&sbp[rb + QA(ws, 0)];           \
          *(float4*)&a8[4] = *(const float4*)&sbp[rb + QA(ws, 1)]; }         \
        split3_pack(a8, u0, u1, u2);                                         \
        const short8v A01 = *(short8v*)&u0, A11 = *(short8v*)&u1, A21 = *(short8v*)&u2; \
        __builtin_amdgcn_s_setprio(1);                                       \
        MFMA6(A00, A10, A20, *(short8v*)&B0v, *(short8v*)&B1v, *(short8v*)&B2v, acc0); \
        MFMA6(A01, A11, A21, *(short8v*)&B0v, *(short8v*)&B1v, *(short8v*)&B2v, acc1); \
        __builtin_amdgcn_s_setprio(0);                                       \
    } while (0)

    // ---- prologue: stage windows 0,1 (slots 0,1) + B(0); one-time drain ----
    LOADB(0);
    DP(0, 0, 0); DP(1, 0, 0); DP(2, 0, 0); DP(3, 0, 0);
    DP(0, 1, 1); DP(1, 1, 1); DP(2, 1, 1); DP(3, 1, 1);
    WAIT0;
    __syncthreads();

    // ---- main: superturns 0..29; uniform WAIT1; stage window st+2 ----
#pragma unroll 1
    for (int st = 0; st < NWIN - 2; ++st) {
        const int p = st % 3, q = (st + 2) % 3, wdw = st + 2;
        const int s0 = st * 4;
        WAIT1; SLICEBODY(s0 + 0, p); LOADB(s0 + 1); DP(0, q, wdw);
        WAIT1; SLICEBODY(s0 + 1, p); LOADB(s0 + 2); DP(1, q, wdw);
        WAIT1; SLICEBODY(s0 + 2, p); LOADB(s0 + 3); DP(2, q, wdw);
        WAIT1; SLICEBODY(s0 + 3, p); LOADB(s0 + 4); DP(3, q, wdw);
        __syncthreads();
    }
    // ---- tail superturn 30 (slices 120..123, slot 0), no staging ----
    WAIT1; SLICEBODY(120, 0); LOADB(121);
    WAIT0; SLICEBODY(121, 0); LOADB(122);
    WAIT0; SLICEBODY(122, 0); LOADB(123);
    WAIT0; SLICEBODY(123, 0); LOADB(124);
    __syncthreads();
    // ---- tail superturn 31 (slices 124..127, slot 1) ----
    WAIT0; SLICEBODY(124, 1); LOADB(125);
    WAIT0; SLICEBODY(125, 1); LOADB(126);
    WAIT0; SLICEBODY(126, 1); LOADB(127);
    WAIT0; SLICEBODY(127, 1);

#undef DP
#undef LOADB
#undef QA
#undef SLICEBODY

    // ---- scores (C/D layout proven r4-r18: token = wr*32+h*16+g*4+q, expert = wc*16+r15)
#pragma unroll
    for (int qi = 0; qi < 4; ++qi) {
        sc[wr * 32 + g * 4 + qi][wc * 16 + r15]      = 1.f / (1.f + expf(-acc0[qi]));
        sc[wr * 32 + 16 + g * 4 + qi][wc * 16 + r15] = 1.f / (1.f + expf(-acc1[qi]));
    }
    __syncthreads();

    // ---- top-8: wave wv handles tokens wv*8..wv*8+7; lane == expert (proven) ----
    const float bias_l = bias[lane];
#pragma unroll 1
    for (int i = 0; i < 8; ++i) {
        const int tok = wv * 8 + i;
        const float sv = sc[tok][lane];
        float myv  = sv + bias_l;
        float outv = 0.f;
        int   outi = 0;
        float sum  = 0.f;
#pragma unroll
        for (int k = 0; k < TOPK; ++k) {
            float cv = myv;
            int   ci = lane;
#pragma unroll
            for (int off = 32; off; off >>= 1) {
                float ov = __shfl_xor(cv, off, 64);
                int   oi = __shfl_xor(ci, off, 64);
                if (ov > cv || (ov == cv && oi < ci)) { cv = ov; ci = oi; }
            }
            float ts = __shfl(sv, ci, 64);     // unbiased score of winner
            sum += ts;
            if (lane == k)  { outv = ts; outi = ci; }
            if (lane == ci) { myv = -1e30f; }
        }
        const float denom = sum + 1e-20f;
        const size_t gt = (size_t)tok0 + tok;
        if (lane < TOPK) {
            out[gt * TOPK + lane] = (outv / denom) * ROUTE_SCALE;
            out[(size_t)NTOK * TOPK + gt * TOPK + lane] = (float)outi;
            atomicAdd(&hist[outi], 1);
        }
    }

    __syncthreads();
    if (t < NE) {
        int cgt = hist[t];
        if (cgt) atomicAdd(&out[(size_t)NTOK * TOPK * 2 + t], (float)cgt);
    }
}

extern "C" void kernel_launch(void* const* d_in, const int* in_sizes, int n_in,
                              void* d_out, int out_size, void* d_ws, size_t ws_size,
                              hipStream_t stream)
{
    const float* x    = (const float*)d_in[0];
    const float* gw   = (const float*)d_in[1];
    const float* bias = (const float*)d_in[2];
    float* out = (float*)d_out;
    uint4* wS  = (uint4*)d_ws;   // 1.5 MB

    // histogram region must start at zero every call
    hipMemsetAsync(out + (size_t)NTOK * TOPK * 2, 0, NE * sizeof(float), stream);

    prep_w<<<128, 256, 0, stream>>>(gw, wS);
    router_fused<<<NTOK / 64, 512, 0, stream>>>(x, wS, bias, out);
}